// Round 2
// 618.377 us; speedup vs baseline: 1.0545x; 1.0545x over previous
//
#include <hip/hip_runtime.h>
#include <cstddef>

// Problem constants
constexpr int HP  = 128 * 128;          // half-res pixels per channel
constexpr long long S = 8LL * 64 * HP;  // elements per (8,64,128,128) buffer

using short8 = __attribute__((ext_vector_type(8))) short;
using f32x4  = __attribute__((ext_vector_type(4))) float;

__device__ __forceinline__ unsigned short f2bf(float x) {
    union { float f; unsigned int u; } v{x};
    unsigned int r = v.u + 0x7FFFu + ((v.u >> 16) & 1u);  // RNE
    return (unsigned short)(r >> 16);
}

// ------------------------------------------------ DWT (Haar) + fused NHWC bf16
// Writes ll planar fp32; lh/hl/hh directly as NHWC bf16 (8,HP,64) via LDS
// transpose. Planar fp32 high-bands are never consumed downstream, so they
// are no longer materialized (saves ~150 MB HBM + 3 kernel launches).
__global__ __launch_bounds__(256) void k_dwt_fused(
        const float* __restrict__ x, float* __restrict__ ll,
        unsigned short* __restrict__ Tlh, unsigned short* __restrict__ Thl,
        unsigned short* __restrict__ Thh) {
    // [64 ch][66] ushort: pad 66 so the transposed read (lane varies c) is
    // conflict-free: bank = (c*33 + (p>>1)) % 32 → 2-way max (free).
    __shared__ unsigned short tlh[64][66];
    __shared__ unsigned short thl[64][66];
    __shared__ unsigned short thh[64][66];
    int b = blockIdx.y;
    int p0 = blockIdx.x * 64;            // 64 consecutive half-res pixels
    int i = p0 >> 7, j0 = p0 & 127;      // output row i, col base j0
    int tid = threadIdx.x;
    {
        int p = tid & 63, c4 = tid >> 6;
        int j = j0 + p;
        const float* xb = x + (size_t)b * 64 * 65536;
#pragma unroll
        for (int k = 0; k < 16; ++k) {
            int c = c4 * 16 + k;
            const float* xp = xb + (size_t)c * 65536;
            float2 top = *(const float2*)(xp + (2 * i) * 256 + 2 * j);
            float2 bot = *(const float2*)(xp + (2 * i + 1) * 256 + 2 * j);
            float a = top.x, bb = top.y, cc = bot.x, dd = bot.y;
            ll[((size_t)b * 64 + c) * HP + p0 + p] = (a + bb + cc + dd) * 0.5f;
            tlh[c][p] = f2bf((a - bb + cc - dd) * 0.5f);
            thl[c][p] = f2bf((a + bb - cc - dd) * 0.5f);
            thh[c][p] = f2bf((a - bb - cc + dd) * 0.5f);
        }
    }
    __syncthreads();
    {
        int c = tid & 63, pq = tid >> 6;
        size_t ob = ((size_t)b * HP + p0) * 64;
#pragma unroll
        for (int k = 0; k < 16; ++k) {
            int p = pq * 16 + k;
            Tlh[ob + (size_t)p * 64 + c] = tlh[c][p];
            Thl[ob + (size_t)p * 64 + c] = thl[c][p];
            Thh[ob + (size_t)p * 64 + c] = thh[c][p];
        }
    }
}

// ------------------------------- weight reorder (oc,ic,3,3) fp32 -> [oc][s*64+ic] bf16
__global__ __launch_bounds__(256) void k_wreorder(const float* __restrict__ w,
                                                  unsigned short* __restrict__ wr, int total) {
    int idx = blockIdx.x * 256 + threadIdx.x;
    if (idx >= total) return;
    int oc = idx / 576, rem = idx - oc * 576;
    int s = rem >> 6, ic = rem & 63;
    wr[idx] = f2bf(w[(oc * 64 + ic) * 9 + s]);
}

// ---------------------- dense attention bias, pre-scaled by temperature
// bd[h][m][n] = table[relidx(n=query, m=key)][h] * temp[h]   (4*64*64 fp32)
__global__ __launch_bounds__(256) void k_bias(const float* __restrict__ table,
                                              const float* __restrict__ temp,
                                              float* __restrict__ bd) {
    int idx = blockIdx.x * 256 + threadIdx.x;   // h*4096 + m*64 + n
    int h = idx >> 12, m = (idx >> 6) & 63, n = idx & 63;
    int i1 = n >> 3, j1 = n & 7, i2 = m >> 3, j2 = m & 7;
    int rel = (i1 - i2 + 7) * 15 + (j1 - j2 + 7);
    bd[idx] = table[rel * 4 + h] * temp[h];
}

// -------------------------- grouped 3x3 conv (+ReLU) via implicit-GEMM MFMA
#define ISTR 72   // per-pixel LDS stride in bf16 (64 data + 8 pad)
__global__ __launch_bounds__(256, 2) void k_conv3x3_mfma(
        const unsigned short* __restrict__ in,
        const unsigned short* __restrict__ wr,
        float* __restrict__ out, int out_ctot) {
    __shared__ __align__(16) unsigned short lin[324 * ISTR];  // 18x18 px halo tile
    __shared__ __align__(16) unsigned short lw[64 * ISTR];    // per-s weights 64oc x 64ic

    int tid = threadIdx.x;
    int b = blockIdx.y;
    int ty0 = (blockIdx.x >> 3) * 16, tx0 = (blockIdx.x & 7) * 16;

    // ---- stage input tile (once): 324 pixel-rows x 128B each
    const unsigned short* inb = in + (size_t)b * HP * 64;
    for (int idx = tid; idx < 324 * 8; idx += 256) {
        int pr = idx >> 3, l8 = idx & 7;
        int py = pr / 18, px = pr - py * 18;
        int gy = ty0 + py - 1, gx = tx0 + px - 1;
        uint4 v = make_uint4(0, 0, 0, 0);
        if (gy >= 0 && gy < 128 && gx >= 0 && gx < 128)
            v = *(const uint4*)(inb + ((size_t)(gy * 128 + gx)) * 64 + l8 * 8);
        *(uint4*)&lin[pr * ISTR + l8 * 8] = v;
    }

    int wv = tid >> 6;
    int lane = tid & 63;
    int n16 = lane & 15, quad = lane >> 4;

    f32x4 acc[4][4];
#pragma unroll
    for (int mt = 0; mt < 4; ++mt)
#pragma unroll
        for (int nt = 0; nt < 4; ++nt) acc[mt][nt] = (f32x4){0.f, 0.f, 0.f, 0.f};

    for (int s = 0; s < 9; ++s) {
        __syncthreads();
        // stage this s's 64x64 weight block
        for (int idx = tid; idx < 512; idx += 256) {
            int oc = idx >> 3, l8 = idx & 7;
            *(uint4*)&lw[oc * ISTR + l8 * 8] =
                *(const uint4*)(wr + oc * 576 + s * 64 + l8 * 8);
        }
        __syncthreads();
        int sy = s / 3, sx = s - sy * 3;
#pragma unroll
        for (int half = 0; half < 2; ++half) {
            int ic0 = half * 32 + quad * 8;
            short8 a[4], bf[4];
#pragma unroll
            for (int mt = 0; mt < 4; ++mt)
                a[mt] = *(const short8*)&lw[(mt * 16 + n16) * ISTR + ic0];
#pragma unroll
            for (int nt = 0; nt < 4; ++nt) {
                int py = 4 * wv + nt + sy;
                int px = n16 + sx;
                bf[nt] = *(const short8*)&lin[(py * 18 + px) * ISTR + ic0];
            }
#pragma unroll
            for (int mt = 0; mt < 4; ++mt)
#pragma unroll
                for (int nt = 0; nt < 4; ++nt)
                    acc[mt][nt] = __builtin_amdgcn_mfma_f32_16x16x32_bf16(
                        a[mt], bf[nt], acc[mt][nt], 0, 0, 0);
        }
    }

    // ---- epilogue: relu + planar fp32 store
    int gx = tx0 + n16;
#pragma unroll
    for (int nt = 0; nt < 4; ++nt) {
        int gy = ty0 + 4 * wv + nt;
#pragma unroll
        for (int mt = 0; mt < 4; ++mt) {
#pragma unroll
            for (int r = 0; r < 4; ++r) {
                int oc = mt * 16 + quad * 4 + r;
                out[((size_t)b * out_ctot + oc) * HP + (size_t)gy * 128 + gx] =
                    fmaxf(acc[mt][nt][r], 0.0f);
            }
        }
    }
}

// ----------------------------------------------------- 1x1 conv, 64 out ch
template <int IC, bool RELU>
__global__ __launch_bounds__(256) void k_conv1x1(const float* __restrict__ in,
                                                 const float* __restrict__ w,
                                                 float* __restrict__ out) {
    __shared__ float wl[IC * 16];
    int tid = threadIdx.x;
    int occ = blockIdx.y, b = blockIdx.z;
    for (int idx = tid; idx < IC * 16; idx += 256) {
        int o = idx & 15, ic = idx >> 4;
        wl[idx] = w[(occ * 16 + o) * IC + ic];
    }
    __syncthreads();
    int p = blockIdx.x * 256 + tid;
    const float* inp = in + (size_t)b * IC * HP + p;
    float acc[16] = {};
    for (int ic = 0; ic < IC; ++ic) {
        float xv = inp[(size_t)ic * HP];
#pragma unroll
        for (int o = 0; o < 16; ++o) acc[o] += xv * wl[ic * 16 + o];
    }
    float* op = out + ((size_t)b * 64 + occ * 16) * HP + p;
#pragma unroll
    for (int o = 0; o < 16; ++o) op[o * HP] = RELU ? fmaxf(acc[o], 0.0f) : acc[o];
}

// ------------------------------- depthwise 3x3 (V slice) fused with v*(1+filt)
__global__ __launch_bounds__(256) void k_dwconv_v(const float* __restrict__ t,
                                                  const float* __restrict__ wdw,
                                                  const float* __restrict__ filt,
                                                  float* __restrict__ v) {
    long long idx = (long long)blockIdx.x * 256 + threadIdx.x;
    if (idx >= S) return;
    int j = (int)(idx & 127);
    int i = (int)((idx >> 7) & 127);
    int c = (int)((idx >> 14) & 63);
    long long bc = idx >> 14;
    const float* tp = t + bc * HP;
    const float* wp = wdw + c * 9;
    float acc = 0.0f;
#pragma unroll
    for (int ky = 0; ky < 3; ++ky) {
        int y = i + ky - 1;
        if (y < 0 || y >= 128) continue;
#pragma unroll
        for (int kx = 0; kx < 3; ++kx) {
            int x = j + kx - 1;
            if (x < 0 || x >= 128) continue;
            acc += tp[y * 128 + x] * wp[ky * 3 + kx];
        }
    }
    float f = filt[idx];
    v[idx] = acc * (1.0f + f);
}

// ---------------------------------------------------- window attention (8x8)
// Chunked online softmax (no p[64] scratch spill), dense pre-scaled bias from
// global (L2-hot, no LDS bank conflicts), vectorized float4 uniform LDS reads.
union F16 { float4 v4[4]; float f[16]; };

__global__ __launch_bounds__(256, 4) void k_attn(const float* __restrict__ ll,
                                                 const float* __restrict__ v,
                                                 const float* __restrict__ bd,
                                                 const float* __restrict__ temp,
                                                 float* __restrict__ outbuf) {
    __shared__ __align__(16) float qs[64][64];
    __shared__ __align__(16) float vs[64][64];
    __shared__ __align__(16) float inv[4][64];
    int blk = blockIdx.x;
    int wj = blk & 15, wi = (blk >> 4) & 15, b = blk >> 8;
    int tid = threadIdx.x;

    for (int idx = tid; idx < 4096; idx += 256) {
        int c = idx >> 6, n = idx & 63;
        int i = n >> 3, j = n & 7;
        int qy = (wi * 8 + i + 4) & 127, qx = (wj * 8 + j + 4) & 127;
        int vy = wi * 8 + i, vx = wj * 8 + j;
        size_t cb = ((size_t)b * 64 + c) * HP;
        qs[c][n] = ll[cb + qy * 128 + qx];
        vs[c][n] = v[cb + vy * 128 + vx];
    }
    __syncthreads();

    int h = tid >> 6, n = tid & 63;
    float tscale = temp[h];
    float q[16];
    float ss = 0.0f;
#pragma unroll
    for (int d = 0; d < 16; ++d) {
        q[d] = qs[h * 16 + d][n];
        ss += q[d] * q[d];
    }
    float invn = 1.0f / fmaxf(sqrtf(ss), 1e-12f);
    inv[h][n] = invn;
    float qsc = invn * tscale;           // fold invn*temp into q
#pragma unroll
    for (int d = 0; d < 16; ++d) q[d] *= qsc;
    __syncthreads();

    const float* bh = bd + (h << 12) + n;
    float mx = -1e30f, sum = 0.0f;
    float acc[16] = {};

    for (int c0 = 0; c0 < 64; c0 += 16) {
        // prefetch bias chunk (coalesced, L2-hot)
        float bb[16];
#pragma unroll
        for (int mm = 0; mm < 16; ++mm) bb[mm] = bh[(c0 + mm) * 64];

        // ---- scores for this m-chunk: s = (q' . qs[:,m]) * inv[m] + bias
        float p[16] = {};
#pragma unroll
        for (int d = 0; d < 16; ++d) {
            F16 A;
            const float4* qr = (const float4*)&qs[h * 16 + d][c0];
            A.v4[0] = qr[0]; A.v4[1] = qr[1]; A.v4[2] = qr[2]; A.v4[3] = qr[3];
            float qd = q[d];
#pragma unroll
            for (int mm = 0; mm < 16; ++mm) p[mm] += qd * A.f[mm];
        }
        F16 I;
        const float4* ir = (const float4*)&inv[h][c0];
        I.v4[0] = ir[0]; I.v4[1] = ir[1]; I.v4[2] = ir[2]; I.v4[3] = ir[3];
        float cm = -1e30f;
#pragma unroll
        for (int mm = 0; mm < 16; ++mm) {
            p[mm] = p[mm] * I.f[mm] + bb[mm];
            cm = fmaxf(cm, p[mm]);
        }

        // ---- online softmax update
        float nm = fmaxf(mx, cm);
        float scale = __expf(mx - nm);   // first chunk: exp(-huge) = 0
        sum *= scale;
#pragma unroll
        for (int mm = 0; mm < 16; ++mm) {
            p[mm] = __expf(p[mm] - nm);
            sum += p[mm];
        }
#pragma unroll
        for (int d = 0; d < 16; ++d) acc[d] *= scale;

        // ---- PV accumulate
#pragma unroll
        for (int d = 0; d < 16; ++d) {
            F16 V;
            const float4* vr = (const float4*)&vs[h * 16 + d][c0];
            V.v4[0] = vr[0]; V.v4[1] = vr[1]; V.v4[2] = vr[2]; V.v4[3] = vr[3];
            float s = acc[d];
#pragma unroll
            for (int mm = 0; mm < 16; ++mm) s += p[mm] * V.f[mm];
            acc[d] = s;
        }
        mx = nm;
    }

    float rs = 1.0f / sum;
    int i1 = n >> 3, j1 = n & 7;
    int oy = (wi * 8 + i1 + 4) & 127, ox = (wj * 8 + j1 + 4) & 127;
#pragma unroll
    for (int d = 0; d < 16; ++d)
        outbuf[((size_t)b * 64 + h * 16 + d) * HP + oy * 128 + ox] = acc[d] * rs;
}

// ---------------------------------------------------------------- IDWT (Haar)
__global__ __launch_bounds__(256) void k_idwt(const float* __restrict__ ll, const float* __restrict__ lh,
                                              const float* __restrict__ hl, const float* __restrict__ hh,
                                              float* __restrict__ out) {
    long long idx = (long long)blockIdx.x * 256 + threadIdx.x;
    if (idx >= S) return;
    int j = (int)(idx & 127);
    int i = (int)((idx >> 7) & 127);
    long long bc = idx >> 14;
    float L = ll[idx], A = lh[idx], B = hl[idx], D = hh[idx];
    float a = (L + A + B + D) * 0.5f;
    float b = (L - A + B - D) * 0.5f;
    float c = (L + A - B - D) * 0.5f;
    float d = (L - A - B + D) * 0.5f;
    float* op = out + bc * 256 * 256;
    *(float2*)(op + (2 * i) * 256 + 2 * j) = make_float2(a, b);
    *(float2*)(op + (2 * i + 1) * 256 + 2 * j) = make_float2(c, d);
}

extern "C" void kernel_launch(void* const* d_in, const int* in_sizes, int n_in,
                              void* d_out, int out_size, void* d_ws, size_t ws_size,
                              hipStream_t stream) {
    const float* x        = (const float*)d_in[0];
    const float* temp     = (const float*)d_in[1];
    const float* table    = (const float*)d_in[2];
    const float* w_high1  = (const float*)d_in[3];  // (128,64,3,3)
    const float* w_high2  = (const float*)d_in[4];  // (64,128,1,1)
    const float* w_highout= (const float*)d_in[5];  // (192,64,3,3)
    const float* w_qkv    = (const float*)d_in[6];  // (192,64,1,1)
    const float* w_dwconv = (const float*)d_in[7];  // (192,1,3,3)
    const float* w_proj   = (const float*)d_in[8];  // (64,64,1,1)
    float* out = (float*)d_out;

    float* ws = (float*)d_ws;
    // 9 slots of S floats, lifetime-reused:
    float* s0 = ws + 0 * S;  // ll (planar fp32)
    float* s1 = ws + 1 * S;  // filt1 ch0..63 -> lh2
    float* s2 = ws + 2 * S;  // filt1 ch64..127 -> hl2
    float* s3 = ws + 3 * S;  // hh2
    float* s4 = ws + 4 * S;  // T_lh (bf16) | T_hl (bf16)
    float* s5 = ws + 5 * S;  // T_hh (bf16) | reordered weights (bf16) | dense bias
    float* s6 = ws + 6 * S;  // filt -> v
    float* s7 = ws + 7 * S;  // t -> attnout
    float* s8 = ws + 8 * S;  // proj out (ll-path into IDWT)

    unsigned short* T_lh = (unsigned short*)s4;
    unsigned short* T_hl = (unsigned short*)s4 + S;
    unsigned short* T_hh = (unsigned short*)s5;
    unsigned short* w_r1 = (unsigned short*)s5 + S;       // 128*576 bf16
    unsigned short* w_r2 = w_r1 + 128 * 576;              // 192*576 bf16
    float* bd = (float*)(w_r2 + 192 * 576);               // 4*64*64 fp32 dense bias

    const int nblk = (int)(S / 256);
    dim3 b256(256);

    // 1. DWT fused with NHWC bf16 transpose of high bands
    dim3 dg(HP / 64, 8);
    k_dwt_fused<<<dg, b256, 0, stream>>>(x, s0, T_lh, T_hl, T_hh);

    // 2. weight reorders + dense bias precompute
    k_wreorder<<<(128 * 576 + 255) / 256, b256, 0, stream>>>(w_high1, w_r1, 128 * 576);
    k_wreorder<<<(192 * 576 + 255) / 256, b256, 0, stream>>>(w_highout, w_r2, 192 * 576);
    k_bias<<<64, b256, 0, stream>>>(table, temp, bd);

    // 3. filt1 = relu(conv3x3 g=2 on [lh,hl]) -> 128ch planar in s1..s2
    dim3 cg(64, 8);
    k_conv3x3_mfma<<<cg, b256, 0, stream>>>(T_lh, w_r1,            s1,            128);
    k_conv3x3_mfma<<<cg, b256, 0, stream>>>(T_hl, w_r1 + 64 * 576, s1 + 64 * HP,  128);

    // 4. filt = relu(1x1 128->64) -> s6
    dim3 g1(64, 4, 8);
    k_conv1x1<128, true><<<g1, b256, 0, stream>>>(s1, w_high2, s6);

    // 5. t = 1x1 conv of ll with V-rows of w_qkv -> s7
    k_conv1x1<64, false><<<g1, b256, 0, stream>>>(s0, w_qkv + 128 * 64, s7);

    // 6. v = dwconv3x3(t) * (1 + filt) -> s6 (in-place over filt)
    k_dwconv_v<<<nblk, b256, 0, stream>>>(s7, w_dwconv + 128 * 9, s6, s6);

    // 7. window attention -> s7
    k_attn<<<2048, b256, 0, stream>>>(s0, s6, bd, temp, s7);

    // 8. proj 1x1 -> s8
    k_conv1x1<64, false><<<g1, b256, 0, stream>>>(s7, w_proj, s8);

    // 9. high-frequency output branch: 3 grouped conv3x3 + relu
    k_conv3x3_mfma<<<cg, b256, 0, stream>>>(T_lh, w_r2,             s1, 64);
    k_conv3x3_mfma<<<cg, b256, 0, stream>>>(T_hl, w_r2 + 64 * 576,  s2, 64);
    k_conv3x3_mfma<<<cg, b256, 0, stream>>>(T_hh, w_r2 + 128 * 576, s3, 64);

    // 10. IDWT -> out
    k_idwt<<<nblk, b256, 0, stream>>>(s8, s1, s2, s3, out);
}

// Round 3
// 608.304 us; speedup vs baseline: 1.0720x; 1.0166x over previous
//
#include <hip/hip_runtime.h>
#include <cstddef>

// Problem constants
constexpr int HP  = 128 * 128;          // half-res pixels per channel
constexpr long long S = 8LL * 64 * HP;  // elements per (8,64,128,128) buffer

using short8 = __attribute__((ext_vector_type(8))) short;
using f32x4  = __attribute__((ext_vector_type(4))) float;

__device__ __forceinline__ unsigned short f2bf(float x) {
    union { float f; unsigned int u; } v{x};
    unsigned int r = v.u + 0x7FFFu + ((v.u >> 16) & 1u);  // RNE
    return (unsigned short)(r >> 16);
}

// ------------------------------------------------ DWT (Haar) + fused NHWC bf16
__global__ __launch_bounds__(256) void k_dwt_fused(
        const float* __restrict__ x, float* __restrict__ ll,
        unsigned short* __restrict__ Tlh, unsigned short* __restrict__ Thl,
        unsigned short* __restrict__ Thh) {
    __shared__ unsigned short tlh[64][66];
    __shared__ unsigned short thl[64][66];
    __shared__ unsigned short thh[64][66];
    int b = blockIdx.y;
    int p0 = blockIdx.x * 64;            // 64 consecutive half-res pixels
    int i = p0 >> 7, j0 = p0 & 127;      // output row i, col base j0
    int tid = threadIdx.x;
    {
        int p = tid & 63, c4 = tid >> 6;
        int j = j0 + p;
        const float* xb = x + (size_t)b * 64 * 65536;
#pragma unroll
        for (int k = 0; k < 16; ++k) {
            int c = c4 * 16 + k;
            const float* xp = xb + (size_t)c * 65536;
            float2 top = *(const float2*)(xp + (2 * i) * 256 + 2 * j);
            float2 bot = *(const float2*)(xp + (2 * i + 1) * 256 + 2 * j);
            float a = top.x, bb = top.y, cc = bot.x, dd = bot.y;
            ll[((size_t)b * 64 + c) * HP + p0 + p] = (a + bb + cc + dd) * 0.5f;
            tlh[c][p] = f2bf((a - bb + cc - dd) * 0.5f);
            thl[c][p] = f2bf((a + bb - cc - dd) * 0.5f);
            thh[c][p] = f2bf((a - bb - cc + dd) * 0.5f);
        }
    }
    __syncthreads();
    {
        int c = tid & 63, pq = tid >> 6;
        size_t ob = ((size_t)b * HP + p0) * 64;
#pragma unroll
        for (int k = 0; k < 16; ++k) {
            int p = pq * 16 + k;
            Tlh[ob + (size_t)p * 64 + c] = tlh[c][p];
            Thl[ob + (size_t)p * 64 + c] = thl[c][p];
            Thh[ob + (size_t)p * 64 + c] = thh[c][p];
        }
    }
}

// ------------------------------- weight reorder (oc,ic,3,3) fp32 -> [oc][s*64+ic] bf16
__global__ __launch_bounds__(256) void k_wreorder(const float* __restrict__ w,
                                                  unsigned short* __restrict__ wr, int total) {
    int idx = blockIdx.x * 256 + threadIdx.x;
    if (idx >= total) return;
    int oc = idx / 576, rem = idx - oc * 576;
    int s = rem >> 6, ic = rem & 63;
    wr[idx] = f2bf(w[(oc * 64 + ic) * 9 + s]);
}

// ---------------------- dense attention bias, pre-scaled by temperature
__global__ __launch_bounds__(256) void k_bias(const float* __restrict__ table,
                                              const float* __restrict__ temp,
                                              float* __restrict__ bd) {
    int idx = blockIdx.x * 256 + threadIdx.x;   // h*4096 + m*64 + n
    int h = idx >> 12, m = (idx >> 6) & 63, n = idx & 63;
    int i1 = n >> 3, j1 = n & 7, i2 = m >> 3, j2 = m & 7;
    int rel = (i1 - i2 + 7) * 15 + (j1 - j2 + 7);
    bd[idx] = table[rel * 4 + h] * temp[h];
}

// -------------------------- grouped 3x3 conv (+ReLU) via implicit-GEMM MFMA
#define ISTR 72   // per-pixel LDS stride in bf16 (64 data + 8 pad)
__global__ __launch_bounds__(256, 2) void k_conv3x3_mfma(
        const unsigned short* __restrict__ in,
        const unsigned short* __restrict__ wr,
        float* __restrict__ out, int out_ctot) {
    __shared__ __align__(16) unsigned short lin[324 * ISTR];  // 18x18 px halo tile
    __shared__ __align__(16) unsigned short lw[64 * ISTR];    // per-s weights 64oc x 64ic

    int tid = threadIdx.x;
    int b = blockIdx.y;
    int ty0 = (blockIdx.x >> 3) * 16, tx0 = (blockIdx.x & 7) * 16;

    const unsigned short* inb = in + (size_t)b * HP * 64;
    for (int idx = tid; idx < 324 * 8; idx += 256) {
        int pr = idx >> 3, l8 = idx & 7;
        int py = pr / 18, px = pr - py * 18;
        int gy = ty0 + py - 1, gx = tx0 + px - 1;
        uint4 v = make_uint4(0, 0, 0, 0);
        if (gy >= 0 && gy < 128 && gx >= 0 && gx < 128)
            v = *(const uint4*)(inb + ((size_t)(gy * 128 + gx)) * 64 + l8 * 8);
        *(uint4*)&lin[pr * ISTR + l8 * 8] = v;
    }

    int wv = tid >> 6;
    int lane = tid & 63;
    int n16 = lane & 15, quad = lane >> 4;

    f32x4 acc[4][4];
#pragma unroll
    for (int mt = 0; mt < 4; ++mt)
#pragma unroll
        for (int nt = 0; nt < 4; ++nt) acc[mt][nt] = (f32x4){0.f, 0.f, 0.f, 0.f};

    for (int s = 0; s < 9; ++s) {
        __syncthreads();
        for (int idx = tid; idx < 512; idx += 256) {
            int oc = idx >> 3, l8 = idx & 7;
            *(uint4*)&lw[oc * ISTR + l8 * 8] =
                *(const uint4*)(wr + oc * 576 + s * 64 + l8 * 8);
        }
        __syncthreads();
        int sy = s / 3, sx = s - sy * 3;
#pragma unroll
        for (int half = 0; half < 2; ++half) {
            int ic0 = half * 32 + quad * 8;
            short8 a[4], bf[4];
#pragma unroll
            for (int mt = 0; mt < 4; ++mt)
                a[mt] = *(const short8*)&lw[(mt * 16 + n16) * ISTR + ic0];
#pragma unroll
            for (int nt = 0; nt < 4; ++nt) {
                int py = 4 * wv + nt + sy;
                int px = n16 + sx;
                bf[nt] = *(const short8*)&lin[(py * 18 + px) * ISTR + ic0];
            }
#pragma unroll
            for (int mt = 0; mt < 4; ++mt)
#pragma unroll
                for (int nt = 0; nt < 4; ++nt)
                    acc[mt][nt] = __builtin_amdgcn_mfma_f32_16x16x32_bf16(
                        a[mt], bf[nt], acc[mt][nt], 0, 0, 0);
        }
    }

    int gx = tx0 + n16;
#pragma unroll
    for (int nt = 0; nt < 4; ++nt) {
        int gy = ty0 + 4 * wv + nt;
#pragma unroll
        for (int mt = 0; mt < 4; ++mt) {
#pragma unroll
            for (int r = 0; r < 4; ++r) {
                int oc = mt * 16 + quad * 4 + r;
                out[((size_t)b * out_ctot + oc) * HP + (size_t)gy * 128 + gx] =
                    fmaxf(acc[mt][nt][r], 0.0f);
            }
        }
    }
}

// ----------------------------------------------------- 1x1 conv, 64 out ch
template <int IC, bool RELU>
__global__ __launch_bounds__(256) void k_conv1x1(const float* __restrict__ in,
                                                 const float* __restrict__ w,
                                                 float* __restrict__ out) {
    __shared__ float wl[IC * 16];
    int tid = threadIdx.x;
    int occ = blockIdx.y, b = blockIdx.z;
    for (int idx = tid; idx < IC * 16; idx += 256) {
        int o = idx & 15, ic = idx >> 4;
        wl[idx] = w[(occ * 16 + o) * IC + ic];
    }
    __syncthreads();
    int p = blockIdx.x * 256 + tid;
    const float* inp = in + (size_t)b * IC * HP + p;
    float acc[16] = {};
    for (int ic = 0; ic < IC; ++ic) {
        float xv = inp[(size_t)ic * HP];
#pragma unroll
        for (int o = 0; o < 16; ++o) acc[o] += xv * wl[ic * 16 + o];
    }
    float* op = out + ((size_t)b * 64 + occ * 16) * HP + p;
#pragma unroll
    for (int o = 0; o < 16; ++o) op[o * HP] = RELU ? fmaxf(acc[o], 0.0f) : acc[o];
}

// ------------------------------- depthwise 3x3 (V slice) fused with v*(1+filt)
__global__ __launch_bounds__(256) void k_dwconv_v(const float* __restrict__ t,
                                                  const float* __restrict__ wdw,
                                                  const float* __restrict__ filt,
                                                  float* __restrict__ v) {
    long long idx = (long long)blockIdx.x * 256 + threadIdx.x;
    if (idx >= S) return;
    int j = (int)(idx & 127);
    int i = (int)((idx >> 7) & 127);
    int c = (int)((idx >> 14) & 63);
    long long bc = idx >> 14;
    const float* tp = t + bc * HP;
    const float* wp = wdw + c * 9;
    float acc = 0.0f;
#pragma unroll
    for (int ky = 0; ky < 3; ++ky) {
        int y = i + ky - 1;
        if (y < 0 || y >= 128) continue;
#pragma unroll
        for (int kx = 0; kx < 3; ++kx) {
            int x = j + kx - 1;
            if (x < 0 || x >= 128) continue;
            acc += tp[y * 128 + x] * wp[ky * 3 + kx];
        }
    }
    float f = filt[idx];
    v[idx] = acc * (1.0f + f);
}

// ------------------------------------- window attention (8x8), 2 windows/block
// 512 threads = 2 windows x 4 heads x 64 positions. 64B-run coalesced global
// access (vs 32B single-window), float4 staging, fused proj 1x1 epilogue
// (proj commutes with window_reverse/roll since it is pointwise).
union F16 { float4 v4[4]; float f[16]; };

__global__ __launch_bounds__(512, 4) void k_attn2(const float* __restrict__ ll,
                                                  const float* __restrict__ v,
                                                  const float* __restrict__ bd,
                                                  const float* __restrict__ temp,
                                                  const float* __restrict__ wproj,
                                                  float* __restrict__ outbuf) {
    __shared__ __align__(16) float qs[64][132];
    __shared__ __align__(16) float vs[64][132];
    __shared__ __align__(16) float inv[4][128];
    int blk = blockIdx.x;
    int wjp = blk & 7, wi = (blk >> 3) & 15, b = blk >> 7;
    int tid = threadIdx.x;

    // ---- stage Q and V: 64 ch x (8 rows x 16 px) in float4 quads
    for (int idx = tid; idx < 2048; idx += 512) {
        int pq = idx & 31, c = idx >> 5;
        int i = pq >> 2, xq = (pq & 3) * 4;         // xq in {0,4,8,12}
        int w = xq >> 3;
        int col = w * 64 + i * 8 + (xq & 7);
        size_t cb = ((size_t)b * 64 + c) * HP;
        int qy = (wi * 8 + i + 4) & 127;
        int qx0 = wjp * 16 + xq + 4;                // may wrap past 127
        int vy = wi * 8 + i, vx0 = wjp * 16 + xq;   // never wraps
        float4 qv;
        if (qx0 <= 124) {
            qv = *(const float4*)(ll + cb + qy * 128 + qx0);
        } else {
            const float* lr = ll + cb + qy * 128;
            qv = make_float4(lr[qx0 & 127], lr[(qx0 + 1) & 127],
                             lr[(qx0 + 2) & 127], lr[(qx0 + 3) & 127]);
        }
        *(float4*)&qs[c][col] = qv;
        *(float4*)&vs[c][col] = *(const float4*)(v + cb + vy * 128 + vx0);
    }
    __syncthreads();

    int n = tid & 63;
    int hw = tid >> 6;           // wave-uniform
    int h = hw & 3, w = hw >> 2;
    int wc = w << 6;
    float tscale = temp[h];
    float q[16];
    float ss = 0.0f;
#pragma unroll
    for (int d = 0; d < 16; ++d) {
        q[d] = qs[h * 16 + d][wc + n];
        ss += q[d] * q[d];
    }
    float invn = 1.0f / fmaxf(sqrtf(ss), 1e-12f);
    inv[h][wc + n] = invn;
    float qsc = invn * tscale;
#pragma unroll
    for (int d = 0; d < 16; ++d) q[d] *= qsc;
    __syncthreads();

    const float* bh = bd + (h << 12) + n;
    float mx = -1e30f, sum = 0.0f;
    float acc[16] = {};

    for (int c0 = 0; c0 < 64; c0 += 16) {
        float bb[16];
#pragma unroll
        for (int mm = 0; mm < 16; ++mm) bb[mm] = bh[(c0 + mm) * 64];

        float p[16] = {};
#pragma unroll
        for (int d = 0; d < 16; ++d) {
            F16 A;
            const float4* qr = (const float4*)&qs[h * 16 + d][wc + c0];
            A.v4[0] = qr[0]; A.v4[1] = qr[1]; A.v4[2] = qr[2]; A.v4[3] = qr[3];
            float qd = q[d];
#pragma unroll
            for (int mm = 0; mm < 16; ++mm) p[mm] += qd * A.f[mm];
        }
        F16 I;
        const float4* ir = (const float4*)&inv[h][wc + c0];
        I.v4[0] = ir[0]; I.v4[1] = ir[1]; I.v4[2] = ir[2]; I.v4[3] = ir[3];
        float cm = -1e30f;
#pragma unroll
        for (int mm = 0; mm < 16; ++mm) {
            p[mm] = p[mm] * I.f[mm] + bb[mm];
            cm = fmaxf(cm, p[mm]);
        }

        float nm = fmaxf(mx, cm);
        float scale = __expf(mx - nm);
        sum *= scale;
#pragma unroll
        for (int mm = 0; mm < 16; ++mm) {
            p[mm] = __expf(p[mm] - nm);
            sum += p[mm];
        }
#pragma unroll
        for (int d = 0; d < 16; ++d) acc[d] *= scale;

#pragma unroll
        for (int d = 0; d < 16; ++d) {
            F16 V;
            const float4* vr = (const float4*)&vs[h * 16 + d][wc + c0];
            V.v4[0] = vr[0]; V.v4[1] = vr[1]; V.v4[2] = vr[2]; V.v4[3] = vr[3];
            float s = acc[d];
#pragma unroll
            for (int mm = 0; mm < 16; ++mm) s += p[mm] * V.f[mm];
            acc[d] = s;
        }
        mx = nm;
    }

    float rs = 1.0f / sum;
    // ---- fused proj: stage attn output back into qs, w_proj into vs space
    __syncthreads();   // all reads of qs/vs complete
#pragma unroll
    for (int d = 0; d < 16; ++d) qs[h * 16 + d][wc + n] = acc[d] * rs;
    float* wl = &vs[0][0];                 // 64x64 = 16 KB overlay
    for (int idx = tid; idx < 4096; idx += 512) wl[idx] = wproj[idx];
    __syncthreads();

    // proj phase: thread -> (h2, pixel p2); lanes sweep x across the window
    // pair so planar stores are 64B runs.
    int h2 = tid >> 7;                     // wave-uniform
    int p2 = tid & 127;
    int i2 = p2 >> 4, xp = p2 & 15;
    int col = ((xp >> 3) << 6) + (i2 << 3) + (xp & 7);
    float po[16] = {};
    for (int ic0 = 0; ic0 < 64; ic0 += 4) {
        float x0 = qs[ic0 + 0][col];
        float x1 = qs[ic0 + 1][col];
        float x2 = qs[ic0 + 2][col];
        float x3 = qs[ic0 + 3][col];
#pragma unroll
        for (int o = 0; o < 16; ++o) {
            float4 wv = *(const float4*)&wl[(h2 * 16 + o) * 64 + ic0];
            po[o] += x0 * wv.x + x1 * wv.y + x2 * wv.z + x3 * wv.w;
        }
    }
    int oy = (wi * 8 + i2 + 4) & 127, ox = (wjp * 16 + xp + 4) & 127;
#pragma unroll
    for (int o = 0; o < 16; ++o)
        outbuf[((size_t)b * 64 + h2 * 16 + o) * HP + oy * 128 + ox] = po[o];
}

// ---------------------------------------------------------------- IDWT (Haar)
// 2 output pixel-pairs per thread, float4 stores.
__global__ __launch_bounds__(256) void k_idwt(const float* __restrict__ ll, const float* __restrict__ lh,
                                              const float* __restrict__ hl, const float* __restrict__ hh,
                                              float* __restrict__ out) {
    long long idx2 = (long long)blockIdx.x * 256 + threadIdx.x;
    if (idx2 >= S / 2) return;
    int j2 = (int)(idx2 & 63);             // half-res col pair
    int i  = (int)((idx2 >> 6) & 127);
    long long bc = idx2 >> 13;
    long long base = bc * HP + i * 128 + 2 * j2;
    float2 L = *(const float2*)(ll + base);
    float2 A = *(const float2*)(lh + base);
    float2 Bv = *(const float2*)(hl + base);
    float2 D = *(const float2*)(hh + base);
    float a0 = (L.x + A.x + Bv.x + D.x) * 0.5f;
    float b0 = (L.x - A.x + Bv.x - D.x) * 0.5f;
    float c0 = (L.x + A.x - Bv.x - D.x) * 0.5f;
    float d0 = (L.x - A.x - Bv.x + D.x) * 0.5f;
    float a1 = (L.y + A.y + Bv.y + D.y) * 0.5f;
    float b1 = (L.y - A.y + Bv.y - D.y) * 0.5f;
    float c1 = (L.y + A.y - Bv.y - D.y) * 0.5f;
    float d1 = (L.y - A.y - Bv.y + D.y) * 0.5f;
    float* op = out + bc * 256 * 256;
    *(float4*)(op + (2 * i) * 256 + 4 * j2)     = make_float4(a0, b0, a1, b1);
    *(float4*)(op + (2 * i + 1) * 256 + 4 * j2) = make_float4(c0, d0, c1, d1);
}

extern "C" void kernel_launch(void* const* d_in, const int* in_sizes, int n_in,
                              void* d_out, int out_size, void* d_ws, size_t ws_size,
                              hipStream_t stream) {
    const float* x        = (const float*)d_in[0];
    const float* temp     = (const float*)d_in[1];
    const float* table    = (const float*)d_in[2];
    const float* w_high1  = (const float*)d_in[3];  // (128,64,3,3)
    const float* w_high2  = (const float*)d_in[4];  // (64,128,1,1)
    const float* w_highout= (const float*)d_in[5];  // (192,64,3,3)
    const float* w_qkv    = (const float*)d_in[6];  // (192,64,1,1)
    const float* w_dwconv = (const float*)d_in[7];  // (192,1,3,3)
    const float* w_proj   = (const float*)d_in[8];  // (64,64,1,1)
    float* out = (float*)d_out;

    float* ws = (float*)d_ws;
    float* s0 = ws + 0 * S;  // ll (planar fp32)
    float* s1 = ws + 1 * S;  // filt1 ch0..63 -> lh2
    float* s2 = ws + 2 * S;  // filt1 ch64..127 -> hl2
    float* s3 = ws + 3 * S;  // hh2
    float* s4 = ws + 4 * S;  // T_lh (bf16) | T_hl (bf16)
    float* s5 = ws + 5 * S;  // T_hh (bf16) | reordered weights (bf16) | dense bias
    float* s6 = ws + 6 * S;  // filt -> v
    float* s7 = ws + 7 * S;  // t
    float* s8 = ws + 8 * S;  // attn+proj out (ll-path into IDWT)

    unsigned short* T_lh = (unsigned short*)s4;
    unsigned short* T_hl = (unsigned short*)s4 + S;
    unsigned short* T_hh = (unsigned short*)s5;
    unsigned short* w_r1 = (unsigned short*)s5 + S;       // 128*576 bf16
    unsigned short* w_r2 = w_r1 + 128 * 576;              // 192*576 bf16
    float* bd = (float*)(w_r2 + 192 * 576);               // 4*64*64 fp32 dense bias

    const int nblk = (int)(S / 256);
    dim3 b256(256);

    // 1. DWT fused with NHWC bf16 transpose of high bands
    dim3 dg(HP / 64, 8);
    k_dwt_fused<<<dg, b256, 0, stream>>>(x, s0, T_lh, T_hl, T_hh);

    // 2. weight reorders + dense bias precompute
    k_wreorder<<<(128 * 576 + 255) / 256, b256, 0, stream>>>(w_high1, w_r1, 128 * 576);
    k_wreorder<<<(192 * 576 + 255) / 256, b256, 0, stream>>>(w_highout, w_r2, 192 * 576);
    k_bias<<<64, b256, 0, stream>>>(table, temp, bd);

    // 3. filt1 = relu(conv3x3 g=2 on [lh,hl]) -> 128ch planar in s1..s2
    dim3 cg(64, 8);
    k_conv3x3_mfma<<<cg, b256, 0, stream>>>(T_lh, w_r1,            s1,            128);
    k_conv3x3_mfma<<<cg, b256, 0, stream>>>(T_hl, w_r1 + 64 * 576, s1 + 64 * HP,  128);

    // 4. filt = relu(1x1 128->64) -> s6
    dim3 g1(64, 4, 8);
    k_conv1x1<128, true><<<g1, b256, 0, stream>>>(s1, w_high2, s6);

    // 5. t = 1x1 conv of ll with V-rows of w_qkv -> s7
    k_conv1x1<64, false><<<g1, b256, 0, stream>>>(s0, w_qkv + 128 * 64, s7);

    // 6. v = dwconv3x3(t) * (1 + filt) -> s6 (in-place over filt)
    k_dwconv_v<<<nblk, b256, 0, stream>>>(s7, w_dwconv + 128 * 9, s6, s6);

    // 7. window attention + fused proj -> s8
    k_attn2<<<1024, dim3(512), 0, stream>>>(s0, s6, bd, temp, w_proj, s8);

    // 8. high-frequency output branch: 3 grouped conv3x3 + relu
    k_conv3x3_mfma<<<cg, b256, 0, stream>>>(T_lh, w_r2,             s1, 64);
    k_conv3x3_mfma<<<cg, b256, 0, stream>>>(T_hl, w_r2 + 64 * 576,  s2, 64);
    k_conv3x3_mfma<<<cg, b256, 0, stream>>>(T_hh, w_r2 + 128 * 576, s3, 64);

    // 9. IDWT -> out
    k_idwt<<<(int)(S / 2 / 256), b256, 0, stream>>>(s8, s1, s2, s3, out);
}

// Round 4
// 559.959 us; speedup vs baseline: 1.1645x; 1.0863x over previous
//
#include <hip/hip_runtime.h>
#include <cstddef>

// Problem constants
constexpr int HP  = 128 * 128;          // half-res pixels per channel
constexpr long long S = 8LL * 64 * HP;  // elements per (8,64,128,128) buffer

using short8 = __attribute__((ext_vector_type(8))) short;
using f32x4  = __attribute__((ext_vector_type(4))) float;

__device__ __forceinline__ unsigned short f2bf(float x) {
    union { float f; unsigned int u; } v{x};
    unsigned int r = v.u + 0x7FFFu + ((v.u >> 16) & 1u);  // RNE
    return (unsigned short)(r >> 16);
}
__device__ __forceinline__ unsigned int pkbf(float a, float b) {
    return (unsigned int)f2bf(a) | ((unsigned int)f2bf(b) << 16);
}

// ------------------------------------------------ DWT (Haar) + fused NHWC bf16
__global__ __launch_bounds__(256) void k_dwt_fused(
        const float* __restrict__ x, float* __restrict__ ll,
        unsigned short* __restrict__ Tlh, unsigned short* __restrict__ Thl,
        unsigned short* __restrict__ Thh) {
    __shared__ unsigned short tlh[64][66];
    __shared__ unsigned short thl[64][66];
    __shared__ unsigned short thh[64][66];
    int b = blockIdx.y;
    int p0 = blockIdx.x * 64;            // 64 consecutive half-res pixels
    int i = p0 >> 7, j0 = p0 & 127;      // output row i, col base j0
    int tid = threadIdx.x;
    {
        int p = tid & 63, c4 = tid >> 6;
        int j = j0 + p;
        const float* xb = x + (size_t)b * 64 * 65536;
#pragma unroll
        for (int k = 0; k < 16; ++k) {
            int c = c4 * 16 + k;
            const float* xp = xb + (size_t)c * 65536;
            float2 top = *(const float2*)(xp + (2 * i) * 256 + 2 * j);
            float2 bot = *(const float2*)(xp + (2 * i + 1) * 256 + 2 * j);
            float a = top.x, bb = top.y, cc = bot.x, dd = bot.y;
            ll[((size_t)b * 64 + c) * HP + p0 + p] = (a + bb + cc + dd) * 0.5f;
            tlh[c][p] = f2bf((a - bb + cc - dd) * 0.5f);
            thl[c][p] = f2bf((a + bb - cc - dd) * 0.5f);
            thh[c][p] = f2bf((a - bb - cc + dd) * 0.5f);
        }
    }
    __syncthreads();
    {
        int c = tid & 63, pq = tid >> 6;
        size_t ob = ((size_t)b * HP + p0) * 64;
#pragma unroll
        for (int k = 0; k < 16; ++k) {
            int p = pq * 16 + k;
            Tlh[ob + (size_t)p * 64 + c] = tlh[c][p];
            Thl[ob + (size_t)p * 64 + c] = thl[c][p];
            Thh[ob + (size_t)p * 64 + c] = thh[c][p];
        }
    }
}

// ------------------------------- weight reorder (oc,ic,3,3) fp32 -> [oc][s*64+ic] bf16
__global__ __launch_bounds__(256) void k_wreorder(const float* __restrict__ w,
                                                  unsigned short* __restrict__ wr, int total) {
    int idx = blockIdx.x * 256 + threadIdx.x;
    if (idx >= total) return;
    int oc = idx / 576, rem = idx - oc * 576;
    int s = rem >> 6, ic = rem & 63;
    wr[idx] = f2bf(w[(oc * 64 + ic) * 9 + s]);
}

// ---------------------- dense attention bias, pre-scaled by temperature
// bd[h*4096 + m*64 + n] = bias[h][n][m] * temp[h]
__global__ __launch_bounds__(256) void k_bias(const float* __restrict__ table,
                                              const float* __restrict__ temp,
                                              float* __restrict__ bd) {
    int idx = blockIdx.x * 256 + threadIdx.x;   // h*4096 + m*64 + n
    int h = idx >> 12, m = (idx >> 6) & 63, n = idx & 63;
    int i1 = n >> 3, j1 = n & 7, i2 = m >> 3, j2 = m & 7;
    int rel = (i1 - i2 + 7) * 15 + (j1 - j2 + 7);
    bd[idx] = table[rel * 4 + h] * temp[h];
}

// -------------------------- grouped 3x3 conv (+ReLU) via implicit-GEMM MFMA
#define ISTR 72   // per-pixel LDS stride in bf16 (64 data + 8 pad)
__global__ __launch_bounds__(256, 2) void k_conv3x3_mfma(
        const unsigned short* __restrict__ in,
        const unsigned short* __restrict__ wr,
        float* __restrict__ out, int out_ctot) {
    __shared__ __align__(16) unsigned short lin[324 * ISTR];  // 18x18 px halo tile
    __shared__ __align__(16) unsigned short lw[64 * ISTR];    // per-s weights 64oc x 64ic

    int tid = threadIdx.x;
    int b = blockIdx.y;
    int ty0 = (blockIdx.x >> 3) * 16, tx0 = (blockIdx.x & 7) * 16;

    const unsigned short* inb = in + (size_t)b * HP * 64;
    for (int idx = tid; idx < 324 * 8; idx += 256) {
        int pr = idx >> 3, l8 = idx & 7;
        int py = pr / 18, px = pr - py * 18;
        int gy = ty0 + py - 1, gx = tx0 + px - 1;
        uint4 v = make_uint4(0, 0, 0, 0);
        if (gy >= 0 && gy < 128 && gx >= 0 && gx < 128)
            v = *(const uint4*)(inb + ((size_t)(gy * 128 + gx)) * 64 + l8 * 8);
        *(uint4*)&lin[pr * ISTR + l8 * 8] = v;
    }

    int wv = tid >> 6;
    int lane = tid & 63;
    int n16 = lane & 15, quad = lane >> 4;

    f32x4 acc[4][4];
#pragma unroll
    for (int mt = 0; mt < 4; ++mt)
#pragma unroll
        for (int nt = 0; nt < 4; ++nt) acc[mt][nt] = (f32x4){0.f, 0.f, 0.f, 0.f};

    for (int s = 0; s < 9; ++s) {
        __syncthreads();
        for (int idx = tid; idx < 512; idx += 256) {
            int oc = idx >> 3, l8 = idx & 7;
            *(uint4*)&lw[oc * ISTR + l8 * 8] =
                *(const uint4*)(wr + oc * 576 + s * 64 + l8 * 8);
        }
        __syncthreads();
        int sy = s / 3, sx = s - sy * 3;
#pragma unroll
        for (int half = 0; half < 2; ++half) {
            int ic0 = half * 32 + quad * 8;
            short8 a[4], bf[4];
#pragma unroll
            for (int mt = 0; mt < 4; ++mt)
                a[mt] = *(const short8*)&lw[(mt * 16 + n16) * ISTR + ic0];
#pragma unroll
            for (int nt = 0; nt < 4; ++nt) {
                int py = 4 * wv + nt + sy;
                int px = n16 + sx;
                bf[nt] = *(const short8*)&lin[(py * 18 + px) * ISTR + ic0];
            }
#pragma unroll
            for (int mt = 0; mt < 4; ++mt)
#pragma unroll
                for (int nt = 0; nt < 4; ++nt)
                    acc[mt][nt] = __builtin_amdgcn_mfma_f32_16x16x32_bf16(
                        a[mt], bf[nt], acc[mt][nt], 0, 0, 0);
        }
    }

    int gx = tx0 + n16;
#pragma unroll
    for (int nt = 0; nt < 4; ++nt) {
        int gy = ty0 + 4 * wv + nt;
#pragma unroll
        for (int mt = 0; mt < 4; ++mt) {
#pragma unroll
            for (int r = 0; r < 4; ++r) {
                int oc = mt * 16 + quad * 4 + r;
                out[((size_t)b * out_ctot + oc) * HP + (size_t)gy * 128 + gx] =
                    fmaxf(acc[mt][nt][r], 0.0f);
            }
        }
    }
}

// ----------------------------------------------------- 1x1 conv, 64 out ch
template <int IC, bool RELU>
__global__ __launch_bounds__(256) void k_conv1x1(const float* __restrict__ in,
                                                 const float* __restrict__ w,
                                                 float* __restrict__ out) {
    __shared__ float wl[IC * 16];
    int tid = threadIdx.x;
    int occ = blockIdx.y, b = blockIdx.z;
    for (int idx = tid; idx < IC * 16; idx += 256) {
        int o = idx & 15, ic = idx >> 4;
        wl[idx] = w[(occ * 16 + o) * IC + ic];
    }
    __syncthreads();
    int p = blockIdx.x * 256 + tid;
    const float* inp = in + (size_t)b * IC * HP + p;
    float acc[16] = {};
    for (int ic = 0; ic < IC; ++ic) {
        float xv = inp[(size_t)ic * HP];
#pragma unroll
        for (int o = 0; o < 16; ++o) acc[o] += xv * wl[ic * 16 + o];
    }
    float* op = out + ((size_t)b * 64 + occ * 16) * HP + p;
#pragma unroll
    for (int o = 0; o < 16; ++o) op[o * HP] = RELU ? fmaxf(acc[o], 0.0f) : acc[o];
}

// ------------------------------- depthwise 3x3 (V slice) fused with v*(1+filt)
__global__ __launch_bounds__(256) void k_dwconv_v(const float* __restrict__ t,
                                                  const float* __restrict__ wdw,
                                                  const float* __restrict__ filt,
                                                  float* __restrict__ v) {
    long long idx = (long long)blockIdx.x * 256 + threadIdx.x;
    if (idx >= S) return;
    int j = (int)(idx & 127);
    int i = (int)((idx >> 7) & 127);
    int c = (int)((idx >> 14) & 63);
    long long bc = idx >> 14;
    const float* tp = t + bc * HP;
    const float* wp = wdw + c * 9;
    float acc = 0.0f;
#pragma unroll
    for (int ky = 0; ky < 3; ++ky) {
        int y = i + ky - 1;
        if (y < 0 || y >= 128) continue;
#pragma unroll
        for (int kx = 0; kx < 3; ++kx) {
            int x = j + kx - 1;
            if (x < 0 || x >= 128) continue;
            acc += tp[y * 128 + x] * wp[ky * 3 + kx];
        }
    }
    float f = filt[idx];
    v[idx] = acc * (1.0f + f);
}

// ---------------------------------- window attention, MFMA (2 windows/block)
// 8 waves = 2 windows x 4 heads. QK^T / PV / fused proj all on
// mfma_f32_16x16x32_bf16 (fragment layouts identical to k_conv3x3_mfma's,
// which is the verified reference: A row=lane&15 k=(lane>>4)*8+e;
// B col=lane&15 same k; C col=lane&15 row=(lane>>4)*4+reg).
// P moves from C-layout to B-fragment layout via 64 in-register shuffles
// (pure lane-group exchange at fixed c) -- no LDS round-trip.
__global__ __launch_bounds__(512, 4) void k_attn_mfma(
        const float* __restrict__ ll, const float* __restrict__ v,
        const float* __restrict__ bd, const float* __restrict__ temp,
        const float* __restrict__ wproj, float* __restrict__ outbuf) {
    __shared__ __align__(16) unsigned char lds[71680];
    float*          qf = (float*)lds;                          // [128][68] fp32 (transient)
    unsigned short* al = (unsigned short*)lds;                 // [128][72] bf16 (reuses qf)
    unsigned short* qt = (unsigned short*)(lds + 34816);       // [128][72] bf16 q*invn
    unsigned short* vt = (unsigned short*)(lds + 53248);       // [128][72] bf16 V

    int blk = blockIdx.x;
    int wjp = blk & 7, wi = (blk >> 3) & 15, b = blk >> 7;
    int tid = threadIdx.x;

    // ---- phase 1: stage Q (fp32, transposed to [px][ch]) and V (bf16 [ch][m])
    for (int idx = tid; idx < 2048; idx += 512) {
        int ch = idx >> 5, pq = idx & 31;
        int i = pq >> 2, xq = (pq & 3) * 4;
        int w = xq >> 3, j0 = xq & 7;
        size_t cb = ((size_t)b * 64 + ch) * HP;
        int qy = (wi * 8 + i + 4) & 127;
        int qx0 = wjp * 16 + xq + 4;
        float4 qv;
        if (qx0 <= 124) {
            qv = *(const float4*)(ll + cb + qy * 128 + qx0);
        } else {
            const float* lr = ll + cb + qy * 128;
            qv = make_float4(lr[qx0 & 127], lr[(qx0 + 1) & 127],
                             lr[(qx0 + 2) & 127], lr[(qx0 + 3) & 127]);
        }
        int np = w * 64 + i * 8 + j0;
        qf[(np    ) * 68 + ch] = qv.x;
        qf[(np + 1) * 68 + ch] = qv.y;
        qf[(np + 2) * 68 + ch] = qv.z;
        qf[(np + 3) * 68 + ch] = qv.w;
        int vy = wi * 8 + i, vx0 = wjp * 16 + xq;
        float4 vv = *(const float4*)(v + cb + vy * 128 + vx0);
        *(uint2*)&vt[(w * 64 + ch) * 72 + i * 8 + j0] =
            make_uint2(pkbf(vv.x, vv.y), pkbf(vv.z, vv.w));
    }
    __syncthreads();

    // ---- phase 2: per-pixel-per-head norm, write bf16 q*invn to qt[px][ch]
    {
        int px = tid >> 2, h = tid & 3;
        const float* qr = qf + px * 68 + h * 16;
        float4 q0 = *(const float4*)(qr);
        float4 q1 = *(const float4*)(qr + 4);
        float4 q2 = *(const float4*)(qr + 8);
        float4 q3 = *(const float4*)(qr + 12);
        float ss = q0.x*q0.x + q0.y*q0.y + q0.z*q0.z + q0.w*q0.w
                 + q1.x*q1.x + q1.y*q1.y + q1.z*q1.z + q1.w*q1.w
                 + q2.x*q2.x + q2.y*q2.y + q2.z*q2.z + q2.w*q2.w
                 + q3.x*q3.x + q3.y*q3.y + q3.z*q3.z + q3.w*q3.w;
        float invn = 1.0f / fmaxf(sqrtf(ss), 1e-12f);
        unsigned short* qo = qt + px * 72 + h * 16;
        *(uint4*)(qo)     = make_uint4(pkbf(q0.x*invn, q0.y*invn), pkbf(q0.z*invn, q0.w*invn),
                                       pkbf(q1.x*invn, q1.y*invn), pkbf(q1.z*invn, q1.w*invn));
        *(uint4*)(qo + 8) = make_uint4(pkbf(q2.x*invn, q2.y*invn), pkbf(q2.z*invn, q2.w*invn),
                                       pkbf(q3.x*invn, q3.y*invn), pkbf(q3.z*invn, q3.w*invn));
    }
    __syncthreads();

    int wv = tid >> 6, lane = tid & 63;
    int h = wv & 3, w = wv >> 2;
    int c = lane & 15, g = lane >> 4;

    // ---- phase 3: QK^T (K=32: 16 real d + 16 zero lanes)
    short8 Fq[4];
#pragma unroll
    for (int t = 0; t < 4; ++t) {
        if (g < 2) Fq[t] = *(const short8*)&qt[(w * 64 + t * 16 + c) * 72 + h * 16 + 8 * g];
        else       Fq[t] = (short8){0, 0, 0, 0, 0, 0, 0, 0};
    }
    f32x4 acc[4][4];   // [ta(m-tile)][tb(n-tile)]
#pragma unroll
    for (int ta = 0; ta < 4; ++ta)
#pragma unroll
        for (int tb = 0; tb < 4; ++tb)
            acc[ta][tb] = __builtin_amdgcn_mfma_f32_16x16x32_bf16(
                Fq[ta], Fq[tb], (f32x4){0.f, 0.f, 0.f, 0.f}, 0, 0, 0);

    // ---- phase 4: bias + softmax (lane holds m = ta*16+4g+r for n = tb*16+c)
    float tscale = temp[h];
    const float* bp = bd + (h << 12) + c;
    float mx[4] = {-1e30f, -1e30f, -1e30f, -1e30f};
#pragma unroll
    for (int ta = 0; ta < 4; ++ta)
#pragma unroll
        for (int tb = 0; tb < 4; ++tb)
#pragma unroll
            for (int r = 0; r < 4; ++r) {
                float s = acc[ta][tb][r] * tscale + bp[(ta * 16 + 4 * g + r) * 64 + tb * 16];
                acc[ta][tb][r] = s;
                mx[tb] = fmaxf(mx[tb], s);
            }
#pragma unroll
    for (int tb = 0; tb < 4; ++tb) {
        mx[tb] = fmaxf(mx[tb], __shfl_xor(mx[tb], 16, 64));
        mx[tb] = fmaxf(mx[tb], __shfl_xor(mx[tb], 32, 64));
    }
    float sum[4] = {0.f, 0.f, 0.f, 0.f};
#pragma unroll
    for (int ta = 0; ta < 4; ++ta)
#pragma unroll
        for (int tb = 0; tb < 4; ++tb)
#pragma unroll
            for (int r = 0; r < 4; ++r) {
                float p = __expf(acc[ta][tb][r] - mx[tb]);
                acc[ta][tb][r] = p;
                sum[tb] += p;
            }
    float rs[4];
#pragma unroll
    for (int tb = 0; tb < 4; ++tb) {
        sum[tb] += __shfl_xor(sum[tb], 16, 64);
        sum[tb] += __shfl_xor(sum[tb], 32, 64);
        rs[tb] = 1.0f / sum[tb];
    }
    unsigned int pk[4][4][2];
#pragma unroll
    for (int tb = 0; tb < 4; ++tb)
#pragma unroll
        for (int ta = 0; ta < 4; ++ta) {
            pk[tb][ta][0] = pkbf(acc[ta][tb][0], acc[ta][tb][1]);
            pk[tb][ta][1] = pkbf(acc[ta][tb][2], acc[ta][tb][3]);
        }

    // ---- phase 5: PV; P reaches B-fragment layout via register shuffles.
    // target lane (g,c), elem e, k-step s: m=32s+8g+e comes from source lane
    // (2(g&1)+(e>>2))*16+c, tile ta=2s+(g>>1), reg r=e&3.
    short8 Va[2];
#pragma unroll
    for (int s = 0; s < 2; ++s)
        Va[s] = *(const short8*)&vt[(w * 64 + h * 16 + c) * 72 + s * 32 + 8 * g];
    int srcA = (2 * (g & 1)) * 16 + c;
    int srcB = srcA + 16;
    int sel = g >> 1;
#pragma unroll
    for (int tb = 0; tb < 4; ++tb) {
        f32x4 po = {0.f, 0.f, 0.f, 0.f};
#pragma unroll
        for (int s = 0; s < 2; ++s) {
            unsigned int a0 = __shfl(pk[tb][2 * s][0], srcA, 64);
            unsigned int b0 = __shfl(pk[tb][2 * s + 1][0], srcA, 64);
            unsigned int a1 = __shfl(pk[tb][2 * s][1], srcA, 64);
            unsigned int b1 = __shfl(pk[tb][2 * s + 1][1], srcA, 64);
            unsigned int a2 = __shfl(pk[tb][2 * s][0], srcB, 64);
            unsigned int b2 = __shfl(pk[tb][2 * s + 1][0], srcB, 64);
            unsigned int a3 = __shfl(pk[tb][2 * s][1], srcB, 64);
            unsigned int b3 = __shfl(pk[tb][2 * s + 1][1], srcB, 64);
            union { short8 s8; unsigned int u[4]; } Bf;
            Bf.u[0] = sel ? b0 : a0;
            Bf.u[1] = sel ? b1 : a1;
            Bf.u[2] = sel ? b2 : a2;
            Bf.u[3] = sel ? b3 : a3;
            po = __builtin_amdgcn_mfma_f32_16x16x32_bf16(Va[s], Bf.s8, po, 0, 0, 0);
        }
        // normalized attn output -> al[px'][ic] bf16 (proj input)
        int px = (2 * tb + (c >> 3)) * 16 + w * 8 + (c & 7);
        *(uint2*)&al[px * 72 + h * 16 + 4 * g] =
            make_uint2(pkbf(po[0] * rs[tb], po[1] * rs[tb]),
                       pkbf(po[2] * rs[tb], po[3] * rs[tb]));
    }
    __syncthreads();

    // ---- phase 6: fused proj 1x1 via MFMA; wave -> (oc-tile, px-half)
    int to = wv & 3, pq2 = wv >> 2;
    short8 Wf[2];
#pragma unroll
    for (int s = 0; s < 2; ++s) {
        const float* wr = wproj + (to * 16 + c) * 64 + s * 32 + 8 * g;
        float4 wa = *(const float4*)(wr);
        float4 wb = *(const float4*)(wr + 4);
        union { short8 s8; unsigned int u[4]; } W;
        W.u[0] = pkbf(wa.x, wa.y); W.u[1] = pkbf(wa.z, wa.w);
        W.u[2] = pkbf(wb.x, wb.y); W.u[3] = pkbf(wb.z, wb.w);
        Wf[s] = W.s8;
    }
#pragma unroll
    for (int t5 = 0; t5 < 4; ++t5) {
        int tp = pq2 * 4 + t5;
        short8 B0 = *(const short8*)&al[(tp * 16 + c) * 72 + 8 * g];
        short8 B1 = *(const short8*)&al[(tp * 16 + c) * 72 + 32 + 8 * g];
        f32x4 po = __builtin_amdgcn_mfma_f32_16x16x32_bf16(
            Wf[0], B0, (f32x4){0.f, 0.f, 0.f, 0.f}, 0, 0, 0);
        po = __builtin_amdgcn_mfma_f32_16x16x32_bf16(Wf[1], B1, po, 0, 0, 0);
        int oy = (wi * 8 + tp + 4) & 127;
        int ox = (wjp * 16 + c + 4) & 127;
        size_t base = ((size_t)b * 64 + to * 16 + 4 * g) * HP + (size_t)oy * 128 + ox;
#pragma unroll
        for (int r = 0; r < 4; ++r) outbuf[base + (size_t)r * HP] = po[r];
    }
}

// ---------------------------------------------------------------- IDWT (Haar)
__global__ __launch_bounds__(256) void k_idwt(const float* __restrict__ ll, const float* __restrict__ lh,
                                              const float* __restrict__ hl, const float* __restrict__ hh,
                                              float* __restrict__ out) {
    long long idx2 = (long long)blockIdx.x * 256 + threadIdx.x;
    if (idx2 >= S / 2) return;
    int j2 = (int)(idx2 & 63);             // half-res col pair
    int i  = (int)((idx2 >> 6) & 127);
    long long bc = idx2 >> 13;
    long long base = bc * HP + i * 128 + 2 * j2;
    float2 L = *(const float2*)(ll + base);
    float2 A = *(const float2*)(lh + base);
    float2 Bv = *(const float2*)(hl + base);
    float2 D = *(const float2*)(hh + base);
    float a0 = (L.x + A.x + Bv.x + D.x) * 0.5f;
    float b0 = (L.x - A.x + Bv.x - D.x) * 0.5f;
    float c0 = (L.x + A.x - Bv.x - D.x) * 0.5f;
    float d0 = (L.x - A.x - Bv.x + D.x) * 0.5f;
    float a1 = (L.y + A.y + Bv.y + D.y) * 0.5f;
    float b1 = (L.y - A.y + Bv.y - D.y) * 0.5f;
    float c1 = (L.y + A.y - Bv.y - D.y) * 0.5f;
    float d1 = (L.y - A.y - Bv.y + D.y) * 0.5f;
    float* op = out + bc * 256 * 256;
    *(float4*)(op + (2 * i) * 256 + 4 * j2)     = make_float4(a0, b0, a1, b1);
    *(float4*)(op + (2 * i + 1) * 256 + 4 * j2) = make_float4(c0, d0, c1, d1);
}

extern "C" void kernel_launch(void* const* d_in, const int* in_sizes, int n_in,
                              void* d_out, int out_size, void* d_ws, size_t ws_size,
                              hipStream_t stream) {
    const float* x        = (const float*)d_in[0];
    const float* temp     = (const float*)d_in[1];
    const float* table    = (const float*)d_in[2];
    const float* w_high1  = (const float*)d_in[3];  // (128,64,3,3)
    const float* w_high2  = (const float*)d_in[4];  // (64,128,1,1)
    const float* w_highout= (const float*)d_in[5];  // (192,64,3,3)
    const float* w_qkv    = (const float*)d_in[6];  // (192,64,1,1)
    const float* w_dwconv = (const float*)d_in[7];  // (192,1,3,3)
    const float* w_proj   = (const float*)d_in[8];  // (64,64,1,1)
    float* out = (float*)d_out;

    float* ws = (float*)d_ws;
    float* s0 = ws + 0 * S;  // ll (planar fp32)
    float* s1 = ws + 1 * S;  // filt1 ch0..63 -> lh2
    float* s2 = ws + 2 * S;  // filt1 ch64..127 -> hl2
    float* s3 = ws + 3 * S;  // hh2
    float* s4 = ws + 4 * S;  // T_lh (bf16) | T_hl (bf16)
    float* s5 = ws + 5 * S;  // T_hh (bf16) | reordered weights (bf16) | dense bias
    float* s6 = ws + 6 * S;  // filt -> v
    float* s7 = ws + 7 * S;  // t
    float* s8 = ws + 8 * S;  // attn+proj out (ll-path into IDWT)

    unsigned short* T_lh = (unsigned short*)s4;
    unsigned short* T_hl = (unsigned short*)s4 + S;
    unsigned short* T_hh = (unsigned short*)s5;
    unsigned short* w_r1 = (unsigned short*)s5 + S;       // 128*576 bf16
    unsigned short* w_r2 = w_r1 + 128 * 576;              // 192*576 bf16
    float* bd = (float*)(w_r2 + 192 * 576);               // 4*64*64 fp32 dense bias

    const int nblk = (int)(S / 256);
    dim3 b256(256);

    // 1. DWT fused with NHWC bf16 transpose of high bands
    dim3 dg(HP / 64, 8);
    k_dwt_fused<<<dg, b256, 0, stream>>>(x, s0, T_lh, T_hl, T_hh);

    // 2. weight reorders + dense bias precompute
    k_wreorder<<<(128 * 576 + 255) / 256, b256, 0, stream>>>(w_high1, w_r1, 128 * 576);
    k_wreorder<<<(192 * 576 + 255) / 256, b256, 0, stream>>>(w_highout, w_r2, 192 * 576);
    k_bias<<<64, b256, 0, stream>>>(table, temp, bd);

    // 3. filt1 = relu(conv3x3 g=2 on [lh,hl]) -> 128ch planar in s1..s2
    dim3 cg(64, 8);
    k_conv3x3_mfma<<<cg, b256, 0, stream>>>(T_lh, w_r1,            s1,            128);
    k_conv3x3_mfma<<<cg, b256, 0, stream>>>(T_hl, w_r1 + 64 * 576, s1 + 64 * HP,  128);

    // 4. filt = relu(1x1 128->64) -> s6
    dim3 g1(64, 4, 8);
    k_conv1x1<128, true><<<g1, b256, 0, stream>>>(s1, w_high2, s6);

    // 5. t = 1x1 conv of ll with V-rows of w_qkv -> s7
    k_conv1x1<64, false><<<g1, b256, 0, stream>>>(s0, w_qkv + 128 * 64, s7);

    // 6. v = dwconv3x3(t) * (1 + filt) -> s6 (in-place over filt)
    k_dwconv_v<<<nblk, b256, 0, stream>>>(s7, w_dwconv + 128 * 9, s6, s6);

    // 7. window attention + fused proj (MFMA) -> s8
    k_attn_mfma<<<1024, dim3(512), 0, stream>>>(s0, s6, bd, temp, w_proj, s8);

    // 8. high-frequency output branch: 3 grouped conv3x3 + relu
    k_conv3x3_mfma<<<cg, b256, 0, stream>>>(T_lh, w_r2,             s1, 64);
    k_conv3x3_mfma<<<cg, b256, 0, stream>>>(T_hl, w_r2 + 64 * 576,  s2, 64);
    k_conv3x3_mfma<<<cg, b256, 0, stream>>>(T_hh, w_r2 + 128 * 576, s3, 64);

    // 9. IDWT -> out
    k_idwt<<<(int)(S / 2 / 256), b256, 0, stream>>>(s8, s1, s2, s3, out);
}